// Round 6
// baseline (744.369 us; speedup 1.0000x reference)
//
#include <hip/hip_runtime.h>
#include <cstdint>

#define SEQ 2048
#define BATCH 2
#define NTOK 4096      // B*S
#define HID 2048
#define NH 32
#define NKV 4
#define HD 128
#define QKV_O 5120     // (32+8)*128

typedef __attribute__((ext_vector_type(8))) short short8;
typedef __attribute__((ext_vector_type(8))) unsigned short u16x8;
typedef __attribute__((ext_vector_type(4))) unsigned short u16x4;
typedef __attribute__((ext_vector_type(4))) float f32x4;

__device__ __forceinline__ float bf2f(unsigned short u) {
  union { unsigned int i; float f; } v; v.i = ((unsigned int)u) << 16; return v.f;
}
__device__ __forceinline__ unsigned short f2bf(float f) {
  union { float f; unsigned int i; } v; v.f = f;
  unsigned int r = v.i + 0x7FFFu + ((v.i >> 16) & 1u);
  return (unsigned short)(r >> 16);
}

// async global->LDS, 16 B per lane. LDS dest is wave-uniform base + lane*16.
__device__ __forceinline__ void load_lds16(const void* g, void* l) {
  __builtin_amdgcn_global_load_lds((const __attribute__((address_space(1))) unsigned int*)g,
                                   (__attribute__((address_space(3))) unsigned int*)l, 16, 0, 0);
}

// ---------------------------------------------------------------------------
// fp32 -> bf16 (round-to-nearest-even), vectorized. n4 = n/4.
// ---------------------------------------------------------------------------
__global__ __launch_bounds__(256) void convert_to_bf16(const float* __restrict__ src,
                                                       unsigned short* __restrict__ dst,
                                                       int n4) {
  int i = blockIdx.x * blockDim.x + threadIdx.x;
  int stride = gridDim.x * blockDim.x;
  for (; i < n4; i += stride) {
    f32x4 v = *(const f32x4*)(src + 4 * (size_t)i);
    u16x4 o;
    o.x = f2bf(v.x); o.y = f2bf(v.y); o.z = f2bf(v.z); o.w = f2bf(v.w);
    *(u16x4*)(dst + 4 * (size_t)i) = o;
  }
}

// ---------------------------------------------------------------------------
// C[M,N] = A[M,K] * B[N,K]^T, bf16 in, fp32 accum, bf16 OR fp32 out (OUT_F32).
// 128x128 tile, BK=32, 4 waves (2x2 of 64x64), mfma_f32_16x16x32_bf16.
// m97-style: global_load_lds width=16 staging into UNPADDED 128x32 LDS.
// ---------------------------------------------------------------------------
template <bool OUT_F32>
__global__ __launch_bounds__(256) void gemm_bt_bf16(
    const unsigned short* __restrict__ A, const unsigned short* __restrict__ B,
    void* __restrict__ Cv, int lda, int ldb, int ldc, int K) {
  __shared__ alignas(16) unsigned short As[128 * 32];
  __shared__ alignas(16) unsigned short Bs[128 * 32];

  const int t    = threadIdx.x;
  const int lane = t & 63;
  const int w    = t >> 6;
  const int wm   = (w >> 1) * 64;
  const int wn   = (w & 1) * 64;
  const size_t m0 = (size_t)blockIdx.y * 128;
  const size_t n0 = (size_t)blockIdx.x * 128;

  f32x4 acc[4][4] = {};

  const int srow = w * 32 + (lane >> 2);
  const int scol = (lane & 3) * 8;
  const unsigned short* gA0 = &A[(m0 + srow) * (size_t)lda + scol];
  const unsigned short* gA1 = gA0 + 16 * (size_t)lda;
  const unsigned short* gB0 = &B[(n0 + srow) * (size_t)ldb + scol];
  const unsigned short* gB1 = gB0 + 16 * (size_t)ldb;
  unsigned short* lA0 = &As[(w * 32) * 32];
  unsigned short* lA1 = &As[(w * 32 + 16) * 32];
  unsigned short* lB0 = &Bs[(w * 32) * 32];
  unsigned short* lB1 = &Bs[(w * 32 + 16) * 32];

  const int fr = lane & 15;
  const int kb = (lane >> 4) * 8;

  for (int k0 = 0; k0 < K; k0 += 32) {
    load_lds16(gA0 + k0, lA0);
    load_lds16(gA1 + k0, lA1);
    load_lds16(gB0 + k0, lB0);
    load_lds16(gB1 + k0, lB1);
    __syncthreads();
    short8 af[4], bf[4];
#pragma unroll
    for (int mt = 0; mt < 4; mt++) af[mt] = *(const short8*)&As[(wm + mt * 16 + fr) * 32 + kb];
#pragma unroll
    for (int nt = 0; nt < 4; nt++) bf[nt] = *(const short8*)&Bs[(wn + nt * 16 + fr) * 32 + kb];
#pragma unroll
    for (int mt = 0; mt < 4; mt++)
#pragma unroll
      for (int nt = 0; nt < 4; nt++)
        acc[mt][nt] = __builtin_amdgcn_mfma_f32_16x16x32_bf16(af[mt], bf[nt], acc[mt][nt], 0, 0, 0);
    __syncthreads();
  }

  const int r4 = (lane >> 4) * 4;
  const int cc = lane & 15;
#pragma unroll
  for (int mt = 0; mt < 4; mt++)
#pragma unroll
    for (int nt = 0; nt < 4; nt++) {
      size_t row = m0 + wm + mt * 16 + r4;
      size_t col = n0 + wn + nt * 16 + cc;
#pragma unroll
      for (int r = 0; r < 4; r++) {
        if (OUT_F32) ((float*)Cv)[(row + r) * ldc + col] = acc[mt][nt][r];
        else ((unsigned short*)Cv)[(row + r) * ldc + col] = f2bf(acc[mt][nt][r]);
      }
    }
}

// ---------------------------------------------------------------------------
// RMSNorm + RoPE, IN PLACE on qkv. One block (4 waves) per token; each wave
// walks 9 of the 36 q+k head slots. cos/sin computed once per lane per block.
// ---------------------------------------------------------------------------
__global__ __launch_bounds__(256) void normrope(
    unsigned short* __restrict__ qkv, const int* __restrict__ pos,
    const unsigned short* __restrict__ qw, const unsigned short* __restrict__ kw) {
  const int tok  = blockIdx.x;
  const int lane = threadIdx.x & 63;
  const int w    = threadIdx.x >> 6;

  const float p = (float)pos[tok];
  const float inv_freq = expf((float)lane * (-13.815510557964274f / 64.0f));  // 1e6^(-lane/64)
  const float ang = p * inv_freq;
  const float co = cosf(ang), si = sinf(ang);

  const float qwl1 = bf2f(qw[lane]), qwl2 = bf2f(qw[lane + 64]);
  const float kwl1 = bf2f(kw[lane]), kwl2 = bf2f(kw[lane + 64]);

  for (int hs = w; hs < NH + NKV; hs += 4) {
    const float w1 = (hs < NH) ? qwl1 : kwl1;
    const float w2 = (hs < NH) ? qwl2 : kwl2;
    const size_t src = (size_t)tok * QKV_O + (size_t)hs * HD;

    float x1 = bf2f(qkv[src + lane]);
    float x2 = bf2f(qkv[src + lane + 64]);
    float ss = x1 * x1 + x2 * x2;
#pragma unroll
    for (int off = 32; off; off >>= 1) ss += __shfl_xor(ss, off);
    float r = rsqrtf(ss * (1.0f / 128.0f) + 1e-6f);
    float n1 = x1 * r * w1;
    float n2 = x2 * r * w2;
    qkv[src + lane]      = f2bf(n1 * co - n2 * si);
    qkv[src + lane + 64] = f2bf(n2 * co + n1 * si);
  }
}

// ---------------------------------------------------------------------------
// V transpose: vt[b][kvh][d][s] <- qkv v-slot. One block per (kv-tile 64, kvh, b).
// ---------------------------------------------------------------------------
__global__ __launch_bounds__(256) void transpose_v(const unsigned short* __restrict__ qkv,
                                                   unsigned short* __restrict__ vt) {
  __shared__ alignas(16) unsigned short Vs[64][136];
  const int k0 = blockIdx.x * 64, kvh = blockIdx.y, b = blockIdx.z;
  const int t = threadIdx.x;
  const int voff = (NH + NKV) * HD + kvh * HD;
  {
    const int row = t >> 2, cb = (t & 3) * 8;
    const size_t gb = (size_t)(b * SEQ + k0 + row) * QKV_O + voff;
#pragma unroll
    for (int r = 0; r < 4; r++)
      *(uint4*)&Vs[row][cb + 32 * r] = *(const uint4*)&qkv[gb + cb + 32 * r];
  }
  __syncthreads();
  const int d = t >> 1, half = t & 1;
  const size_t ob = ((size_t)((b * NKV + kvh) * HD + d)) * SEQ + k0 + half * 32;
#pragma unroll
  for (int i = 0; i < 4; i++) {
    u16x8 vv;
#pragma unroll
    for (int j = 0; j < 8; j++) vv[j] = Vs[half * 32 + i * 8 + j][d];
    *(u16x8*)&vt[ob + i * 8] = vv;
  }
}

// ---------------------------------------------------------------------------
// MFMA causal GQA flash attention (v3): 2 q-groups per wave.
// Block: 256 thr (4 waves), q-tile 128 (wave w: rows q0+32w..+31, as 2 groups
// of 16), KV tiles 64. ScT[kv][q] = K @ Q^T per group, sharing each kf LDS
// read across both groups (2 MFMAs per fragment read). Per-q softmax in-lane
// over 16 regs + shfl_xor(16,32); alpha/l column->row rebroadcast via shfl.
// P -> per-wave LDS (A-frag); PV shares each vf read across both groups.
// ---------------------------------------------------------------------------
__global__ __launch_bounds__(256) void flash_mfma(unsigned short* __restrict__ qkv,
                                                  const unsigned short* __restrict__ vt) {
  __shared__ alignas(16) unsigned short Ks[64][136];
  __shared__ alignas(16) unsigned short Vt[128][72];
  __shared__ alignas(16) unsigned short Ps[4][2][16][72];

  const int qt = (int)gridDim.x - 1 - (int)blockIdx.x; // heavy blocks first
  const int h = blockIdx.y, b = blockIdx.z;
  const int t = threadIdx.x;
  const int lane = t & 63, w = t >> 6;
  const int c = lane & 15, g = lane >> 4;
  const int q0 = qt * 128;
  const int kvh = h >> 3;                              // GQA 32->4
  const int koff = NH * HD + kvh * HD;
  const float scale = 0.08838834764831845f;            // 128^-0.5

  // Q B-frags straight from global (one-time, 8 x 16B per lane)
  short8 qf[2][4];
#pragma unroll
  for (int grp = 0; grp < 2; grp++) {
    const size_t qrow = (size_t)(b * SEQ + q0 + w * 32 + grp * 16 + c) * QKV_O + h * HD;
#pragma unroll
    for (int ks = 0; ks < 4; ks++)
      qf[grp][ks] = *(const short8*)&qkv[qrow + ks * 32 + g * 8];
  }

  f32x4 O[2][8] = {};                       // per group: 8 d-tiles x 4 row-regs
  float m_i[2] = {-1e30f, -1e30f}, l_i[2] = {0.0f, 0.0f};

  const int nkt = 2 * qt + 2;
  for (int kt = 0; kt < nkt; kt++) {
    const int k0 = kt * 64;
    __syncthreads();
    // stage K rows (coalesced uint4)
    {
      const int row = t >> 2, cb = (t & 3) * 8;
      const size_t gb = (size_t)(b * SEQ + k0 + row) * QKV_O + koff;
#pragma unroll
      for (int r = 0; r < 4; r++)
        *(uint4*)&Ks[row][cb + 32 * r] = *(const uint4*)&qkv[gb + cb + 32 * r];
    }
    // stage Vt tile from pre-transposed global (coalesced uint4)
    {
      const int d = t >> 1, half = t & 1;
      const size_t gb = ((size_t)((b * NKV + kvh) * HD + d)) * SEQ + k0 + half * 32;
#pragma unroll
      for (int i = 0; i < 4; i++)
        *(uint4*)&Vt[d][half * 32 + i * 8] = *(const uint4*)&vt[gb + i * 8];
    }
    __syncthreads();

    // ScT[kv 64][q 16] x2 groups: each kf read feeds 2 MFMAs
    f32x4 sc[2][4];
#pragma unroll
    for (int grp = 0; grp < 2; grp++)
#pragma unroll
      for (int mt = 0; mt < 4; mt++) sc[grp][mt] = (f32x4){0.f, 0.f, 0.f, 0.f};
#pragma unroll
    for (int ks = 0; ks < 4; ks++) {
#pragma unroll
      for (int mt = 0; mt < 4; mt++) {
        short8 kf = *(const short8*)&Ks[mt * 16 + c][ks * 32 + g * 8];
        sc[0][mt] = __builtin_amdgcn_mfma_f32_16x16x32_bf16(kf, qf[0][ks], sc[0][mt], 0, 0, 0);
        sc[1][mt] = __builtin_amdgcn_mfma_f32_16x16x32_bf16(kf, qf[1][ks], sc[1][mt], 0, 0, 0);
      }
    }

#pragma unroll
    for (int grp = 0; grp < 2; grp++) {
      const int qrow = q0 + w * 32 + grp * 16 + c;
      const bool need_mask = (k0 + 63 > q0 + w * 32 + grp * 16);
      float scv[16];
#pragma unroll
      for (int mt = 0; mt < 4; mt++)
#pragma unroll
        for (int r = 0; r < 4; r++) {
          float s = sc[grp][mt][r] * scale;
          if (need_mask && (k0 + mt * 16 + g * 4 + r > qrow)) s = -1e30f;
          scv[mt * 4 + r] = s;
        }

      // per-q (column) online softmax
      float mx = scv[0];
#pragma unroll
      for (int i = 1; i < 16; i++) mx = fmaxf(mx, scv[i]);
      mx = fmaxf(mx, __shfl_xor(mx, 16));
      mx = fmaxf(mx, __shfl_xor(mx, 32));
      float m_new = fmaxf(m_i[grp], mx);
      float alpha = __expf(m_i[grp] - m_new);
      float psum = 0.0f;
      unsigned short pb[16];
#pragma unroll
      for (int i = 0; i < 16; i++) {
        float p = __expf(scv[i] - m_new);
        psum += p;
        pb[i] = f2bf(p);
      }
      psum += __shfl_xor(psum, 16);
      psum += __shfl_xor(psum, 32);
      l_i[grp] = l_i[grp] * alpha + psum;
      m_i[grp] = m_new;

      // write P[q][kv] bf16 into per-wave/per-group region
#pragma unroll
      for (int mt = 0; mt < 4; mt++) {
        u16x4 p4 = {pb[mt * 4 + 0], pb[mt * 4 + 1], pb[mt * 4 + 2], pb[mt * 4 + 3]};
        *(u16x4*)&Ps[w][grp][c][mt * 16 + g * 4] = p4;
      }
      // rebroadcast alpha from col-space (q=c) to row-space (q=g*4+r) via shfl
      f32x4 a4;
#pragma unroll
      for (int r = 0; r < 4; r++) a4[r] = __shfl(alpha, g * 4 + r);
#pragma unroll
      for (int nt = 0; nt < 8; nt++)
#pragma unroll
        for (int r = 0; r < 4; r++) O[grp][nt][r] *= a4[r];
    }

    // PV: each vf read feeds 2 MFMAs; 2 ks x 8 nt x 2 grp
#pragma unroll
    for (int ks = 0; ks < 2; ks++) {
      short8 pf0 = *(const short8*)&Ps[w][0][c][ks * 32 + g * 8];
      short8 pf1 = *(const short8*)&Ps[w][1][c][ks * 32 + g * 8];
#pragma unroll
      for (int nt = 0; nt < 8; nt++) {
        short8 vf = *(const short8*)&Vt[nt * 16 + c][ks * 32 + g * 8];
        O[0][nt] = __builtin_amdgcn_mfma_f32_16x16x32_bf16(pf0, vf, O[0][nt], 0, 0, 0);
        O[1][nt] = __builtin_amdgcn_mfma_f32_16x16x32_bf16(pf1, vf, O[1][nt], 0, 0, 0);
      }
    }
  }

  // epilogue: O /= l (shfl rebroadcast), write bf16 in place (q region)
#pragma unroll
  for (int grp = 0; grp < 2; grp++) {
    f32x4 li;
#pragma unroll
    for (int r = 0; r < 4; r++) li[r] = 1.0f / __shfl(l_i[grp], g * 4 + r);
#pragma unroll
    for (int nt = 0; nt < 8; nt++)
#pragma unroll
      for (int r = 0; r < 4; r++) {
        size_t addr = (size_t)(b * SEQ + q0 + w * 32 + grp * 16 + g * 4 + r) * QKV_O
                      + h * HD + nt * 16 + c;
        qkv[addr] = f2bf(O[grp][nt][r] * li[r]);
      }
  }
}

// ---------------------------------------------------------------------------
extern "C" void kernel_launch(void* const* d_in, const int* in_sizes, int n_in,
                              void* d_out, int out_size, void* d_ws, size_t ws_size,
                              hipStream_t stream) {
  const float* hidden_f = (const float*)d_in[0];
  const int* positions  = (const int*)d_in[1];
  const float* wqkv_f   = (const float*)d_in[2];
  const float* wo_f     = (const float*)d_in[3];
  const float* qn_f     = (const float*)d_in[4];
  const float* kn_f     = (const float*)d_in[5];
  float* out            = (float*)d_out;  // reference output dtype is float32

  char* ws = (char*)d_ws;
  unsigned short* hidden_c = (unsigned short*)ws;                    // 16,777,216
  unsigned short* wqkv_c   = (unsigned short*)(ws + 16777216);       // 20,971,520
  unsigned short* wo_c     = (unsigned short*)(ws + 37748736);       // 16,777,216
  unsigned short* qn_c     = (unsigned short*)(ws + 54525952);       // 256
  unsigned short* kn_c     = (unsigned short*)(ws + 54526208);       // 256
  unsigned short* qkv      = (unsigned short*)(ws + 54526464);       // 41,943,040
  unsigned short* vt_g     = (unsigned short*)(ws + 96469504);       // 4,194,304  (total ~96 MiB)

  convert_to_bf16<<<1024, 256, 0, stream>>>(hidden_f, hidden_c, NTOK * HID / 4);
  convert_to_bf16<<<1024, 256, 0, stream>>>(wqkv_f, wqkv_c, QKV_O * HID / 4);
  convert_to_bf16<<<1024, 256, 0, stream>>>(wo_f, wo_c, HID * NH * HD / 4);
  convert_to_bf16<<<1, 32, 0, stream>>>(qn_f, qn_c, HD / 4);
  convert_to_bf16<<<1, 32, 0, stream>>>(kn_f, kn_c, HD / 4);

  // K1: qkv = hidden @ w_qkv^T   (4096 x 5120 x 2048), bf16 out
  gemm_bt_bf16<false><<<dim3(QKV_O / 128, NTOK / 128), 256, 0, stream>>>(
      hidden_c, wqkv_c, qkv, HID, HID, QKV_O, HID);
  // K2: rmsnorm + rope, in place on q & k head slots
  normrope<<<NTOK, 256, 0, stream>>>(qkv, positions, qn_c, kn_c);
  // K2b: V transpose into vt_g
  transpose_v<<<dim3(SEQ / 64, NKV, BATCH), 256, 0, stream>>>(qkv, vt_g);
  // K3: MFMA causal GQA attention, attn in place into q region of qkv
  flash_mfma<<<dim3(SEQ / 128, NH, BATCH), 256, 0, stream>>>(qkv, vt_g);
  // K4: out = attn @ w_o^T   (4096 x 2048 x 4096), fp32 out
  gemm_bt_bf16<true><<<dim3(HID / 128, NTOK / 128), 256, 0, stream>>>(
      qkv, wo_c, out, QKV_O, NH * HD, HID, NH * HD);
}

// Round 7
// 742.415 us; speedup vs baseline: 1.0026x; 1.0026x over previous
//
#include <hip/hip_runtime.h>
#include <cstdint>

#define SEQ 2048
#define BATCH 2
#define NTOK 4096      // B*S
#define HID 2048
#define NH 32
#define NKV 4
#define HD 128
#define QKV_O 5120     // (32+8)*128

typedef __attribute__((ext_vector_type(8))) short short8;
typedef __attribute__((ext_vector_type(8))) unsigned short u16x8;
typedef __attribute__((ext_vector_type(4))) unsigned short u16x4;
typedef __attribute__((ext_vector_type(4))) float f32x4;

__device__ __forceinline__ float bf2f(unsigned short u) {
  union { unsigned int i; float f; } v; v.i = ((unsigned int)u) << 16; return v.f;
}
__device__ __forceinline__ unsigned short f2bf(float f) {
  union { float f; unsigned int i; } v; v.f = f;
  unsigned int r = v.i + 0x7FFFu + ((v.i >> 16) & 1u);
  return (unsigned short)(r >> 16);
}

// async global->LDS, 16 B per lane. LDS dest is wave-uniform base + lane*16.
__device__ __forceinline__ void load_lds16(const void* g, void* l) {
  __builtin_amdgcn_global_load_lds((const __attribute__((address_space(1))) unsigned int*)g,
                                   (__attribute__((address_space(3))) unsigned int*)l, 16, 0, 0);
}

// ---------------------------------------------------------------------------
// fp32 -> bf16 (round-to-nearest-even), vectorized. n4 = n/4.
// ---------------------------------------------------------------------------
__global__ __launch_bounds__(256) void convert_to_bf16(const float* __restrict__ src,
                                                       unsigned short* __restrict__ dst,
                                                       int n4) {
  int i = blockIdx.x * blockDim.x + threadIdx.x;
  int stride = gridDim.x * blockDim.x;
  for (; i < n4; i += stride) {
    f32x4 v = *(const f32x4*)(src + 4 * (size_t)i);
    u16x4 o;
    o.x = f2bf(v.x); o.y = f2bf(v.y); o.z = f2bf(v.z); o.w = f2bf(v.w);
    *(u16x4*)(dst + 4 * (size_t)i) = o;
  }
}

// ---------------------------------------------------------------------------
// C[M,N] = A[M,K] * B[N,K]^T, bf16 in, fp32 accum, bf16 OR fp32 out (OUT_F32).
// 128x128 tile, BK=32, 4 waves (2x2 of 64x64), mfma_f32_16x16x32_bf16.
// m97-style: global_load_lds width=16 staging into UNPADDED 128x32 LDS.
// ---------------------------------------------------------------------------
template <bool OUT_F32>
__global__ __launch_bounds__(256) void gemm_bt_bf16(
    const unsigned short* __restrict__ A, const unsigned short* __restrict__ B,
    void* __restrict__ Cv, int lda, int ldb, int ldc, int K) {
  __shared__ alignas(16) unsigned short As[128 * 32];
  __shared__ alignas(16) unsigned short Bs[128 * 32];

  const int t    = threadIdx.x;
  const int lane = t & 63;
  const int w    = t >> 6;
  const int wm   = (w >> 1) * 64;
  const int wn   = (w & 1) * 64;
  const size_t m0 = (size_t)blockIdx.y * 128;
  const size_t n0 = (size_t)blockIdx.x * 128;

  f32x4 acc[4][4] = {};

  const int srow = w * 32 + (lane >> 2);
  const int scol = (lane & 3) * 8;
  const unsigned short* gA0 = &A[(m0 + srow) * (size_t)lda + scol];
  const unsigned short* gA1 = gA0 + 16 * (size_t)lda;
  const unsigned short* gB0 = &B[(n0 + srow) * (size_t)ldb + scol];
  const unsigned short* gB1 = gB0 + 16 * (size_t)ldb;
  unsigned short* lA0 = &As[(w * 32) * 32];
  unsigned short* lA1 = &As[(w * 32 + 16) * 32];
  unsigned short* lB0 = &Bs[(w * 32) * 32];
  unsigned short* lB1 = &Bs[(w * 32 + 16) * 32];

  const int fr = lane & 15;
  const int kb = (lane >> 4) * 8;

  for (int k0 = 0; k0 < K; k0 += 32) {
    load_lds16(gA0 + k0, lA0);
    load_lds16(gA1 + k0, lA1);
    load_lds16(gB0 + k0, lB0);
    load_lds16(gB1 + k0, lB1);
    __syncthreads();
    short8 af[4], bf[4];
#pragma unroll
    for (int mt = 0; mt < 4; mt++) af[mt] = *(const short8*)&As[(wm + mt * 16 + fr) * 32 + kb];
#pragma unroll
    for (int nt = 0; nt < 4; nt++) bf[nt] = *(const short8*)&Bs[(wn + nt * 16 + fr) * 32 + kb];
#pragma unroll
    for (int mt = 0; mt < 4; mt++)
#pragma unroll
      for (int nt = 0; nt < 4; nt++)
        acc[mt][nt] = __builtin_amdgcn_mfma_f32_16x16x32_bf16(af[mt], bf[nt], acc[mt][nt], 0, 0, 0);
    __syncthreads();
  }

  const int r4 = (lane >> 4) * 4;
  const int cc = lane & 15;
#pragma unroll
  for (int mt = 0; mt < 4; mt++)
#pragma unroll
    for (int nt = 0; nt < 4; nt++) {
      size_t row = m0 + wm + mt * 16 + r4;
      size_t col = n0 + wn + nt * 16 + cc;
#pragma unroll
      for (int r = 0; r < 4; r++) {
        if (OUT_F32) ((float*)Cv)[(row + r) * ldc + col] = acc[mt][nt][r];
        else ((unsigned short*)Cv)[(row + r) * ldc + col] = f2bf(acc[mt][nt][r]);
      }
    }
}

// ---------------------------------------------------------------------------
// RMSNorm + RoPE, IN PLACE on qkv. One block (4 waves) per token; each wave
// walks 9 of the 36 q+k head slots. cos/sin computed once per lane per block.
// ---------------------------------------------------------------------------
__global__ __launch_bounds__(256) void normrope(
    unsigned short* __restrict__ qkv, const int* __restrict__ pos,
    const unsigned short* __restrict__ qw, const unsigned short* __restrict__ kw) {
  const int tok  = blockIdx.x;
  const int lane = threadIdx.x & 63;
  const int w    = threadIdx.x >> 6;

  const float p = (float)pos[tok];
  const float inv_freq = expf((float)lane * (-13.815510557964274f / 64.0f));  // 1e6^(-lane/64)
  const float ang = p * inv_freq;
  const float co = cosf(ang), si = sinf(ang);

  const float qwl1 = bf2f(qw[lane]), qwl2 = bf2f(qw[lane + 64]);
  const float kwl1 = bf2f(kw[lane]), kwl2 = bf2f(kw[lane + 64]);

  for (int hs = w; hs < NH + NKV; hs += 4) {
    const float w1 = (hs < NH) ? qwl1 : kwl1;
    const float w2 = (hs < NH) ? qwl2 : kwl2;
    const size_t src = (size_t)tok * QKV_O + (size_t)hs * HD;

    float x1 = bf2f(qkv[src + lane]);
    float x2 = bf2f(qkv[src + lane + 64]);
    float ss = x1 * x1 + x2 * x2;
#pragma unroll
    for (int off = 32; off; off >>= 1) ss += __shfl_xor(ss, off);
    float r = rsqrtf(ss * (1.0f / 128.0f) + 1e-6f);
    float n1 = x1 * r * w1;
    float n2 = x2 * r * w2;
    qkv[src + lane]      = f2bf(n1 * co - n2 * si);
    qkv[src + lane + 64] = f2bf(n2 * co + n1 * si);
  }
}

// ---------------------------------------------------------------------------
// V transpose: vt[b][kvh][d][s] <- qkv v-slot. One block per (kv-tile 64, kvh, b).
// ---------------------------------------------------------------------------
__global__ __launch_bounds__(256) void transpose_v(const unsigned short* __restrict__ qkv,
                                                   unsigned short* __restrict__ vt) {
  __shared__ alignas(16) unsigned short Vs[64][136];
  const int k0 = blockIdx.x * 64, kvh = blockIdx.y, b = blockIdx.z;
  const int t = threadIdx.x;
  const int voff = (NH + NKV) * HD + kvh * HD;
  {
    const int row = t >> 2, cb = (t & 3) * 8;
    const size_t gb = (size_t)(b * SEQ + k0 + row) * QKV_O + voff;
#pragma unroll
    for (int r = 0; r < 4; r++)
      *(uint4*)&Vs[row][cb + 32 * r] = *(const uint4*)&qkv[gb + cb + 32 * r];
  }
  __syncthreads();
  const int d = t >> 1, half = t & 1;
  const size_t ob = ((size_t)((b * NKV + kvh) * HD + d)) * SEQ + k0 + half * 32;
#pragma unroll
  for (int i = 0; i < 4; i++) {
    u16x8 vv;
#pragma unroll
    for (int j = 0; j < 8; j++) vv[j] = Vs[half * 32 + i * 8 + j][d];
    *(u16x8*)&vt[ob + i * 8] = vv;
  }
}

// ---------------------------------------------------------------------------
// MFMA causal GQA flash attention (v4): 2 q-groups per wave, SINGLE-buffered
// Ps (PV runs group 0 then group 1, reusing one per-wave P region).
// Block: 256 thr (4 waves), q-tile 128 (wave w: rows q0+32w..+31 as 2 groups
// of 16), KV tiles 64. QK^T shares each kf LDS read across both groups.
// LDS = 17408 + 18432 + 9216 = 45,056 B -> 3 blocks/CU (12 waves).
// __launch_bounds__(256,3) caps VGPR at 170 so registers can't re-cap occ.
// ---------------------------------------------------------------------------
__global__ __launch_bounds__(256, 3) void flash_mfma(unsigned short* __restrict__ qkv,
                                                     const unsigned short* __restrict__ vt) {
  __shared__ alignas(16) unsigned short Ks[64][136];
  __shared__ alignas(16) unsigned short Vt[128][72];
  __shared__ alignas(16) unsigned short Ps[4][16][72];

  const int qt = (int)gridDim.x - 1 - (int)blockIdx.x; // heavy blocks first
  const int h = blockIdx.y, b = blockIdx.z;
  const int t = threadIdx.x;
  const int lane = t & 63, w = t >> 6;
  const int c = lane & 15, g = lane >> 4;
  const int q0 = qt * 128;
  const int kvh = h >> 3;                              // GQA 32->4
  const int koff = NH * HD + kvh * HD;
  const float scale = 0.08838834764831845f;            // 128^-0.5

  // Q B-frags straight from global (one-time, 8 x 16B per lane)
  short8 qf[2][4];
#pragma unroll
  for (int grp = 0; grp < 2; grp++) {
    const size_t qrow = (size_t)(b * SEQ + q0 + w * 32 + grp * 16 + c) * QKV_O + h * HD;
#pragma unroll
    for (int ks = 0; ks < 4; ks++)
      qf[grp][ks] = *(const short8*)&qkv[qrow + ks * 32 + g * 8];
  }

  f32x4 O[2][8] = {};                       // per group: 8 d-tiles x 4 row-regs
  float m_i[2] = {-1e30f, -1e30f}, l_i[2] = {0.0f, 0.0f};

  const int nkt = 2 * qt + 2;
  for (int kt = 0; kt < nkt; kt++) {
    const int k0 = kt * 64;
    __syncthreads();
    // stage K rows (coalesced uint4)
    {
      const int row = t >> 2, cb = (t & 3) * 8;
      const size_t gb = (size_t)(b * SEQ + k0 + row) * QKV_O + koff;
#pragma unroll
      for (int r = 0; r < 4; r++)
        *(uint4*)&Ks[row][cb + 32 * r] = *(const uint4*)&qkv[gb + cb + 32 * r];
    }
    // stage Vt tile from pre-transposed global (coalesced uint4)
    {
      const int d = t >> 1, half = t & 1;
      const size_t gb = ((size_t)((b * NKV + kvh) * HD + d)) * SEQ + k0 + half * 32;
#pragma unroll
      for (int i = 0; i < 4; i++)
        *(uint4*)&Vt[d][half * 32 + i * 8] = *(const uint4*)&vt[gb + i * 8];
    }
    __syncthreads();

    // ScT[kv 64][q 16] x2 groups: each kf read feeds 2 MFMAs
    f32x4 sc[2][4];
#pragma unroll
    for (int grp = 0; grp < 2; grp++)
#pragma unroll
      for (int mt = 0; mt < 4; mt++) sc[grp][mt] = (f32x4){0.f, 0.f, 0.f, 0.f};
#pragma unroll
    for (int ks = 0; ks < 4; ks++) {
#pragma unroll
      for (int mt = 0; mt < 4; mt++) {
        short8 kf = *(const short8*)&Ks[mt * 16 + c][ks * 32 + g * 8];
        sc[0][mt] = __builtin_amdgcn_mfma_f32_16x16x32_bf16(kf, qf[0][ks], sc[0][mt], 0, 0, 0);
        sc[1][mt] = __builtin_amdgcn_mfma_f32_16x16x32_bf16(kf, qf[1][ks], sc[1][mt], 0, 0, 0);
      }
    }

    // softmax both groups (results held in regs), then sequential PV
    unsigned short pb[2][16];
#pragma unroll
    for (int grp = 0; grp < 2; grp++) {
      const int qrow = q0 + w * 32 + grp * 16 + c;
      const bool need_mask = (k0 + 63 > q0 + w * 32 + grp * 16);
      float scv[16];
#pragma unroll
      for (int mt = 0; mt < 4; mt++)
#pragma unroll
        for (int r = 0; r < 4; r++) {
          float s = sc[grp][mt][r] * scale;
          if (need_mask && (k0 + mt * 16 + g * 4 + r > qrow)) s = -1e30f;
          scv[mt * 4 + r] = s;
        }

      float mx = scv[0];
#pragma unroll
      for (int i = 1; i < 16; i++) mx = fmaxf(mx, scv[i]);
      mx = fmaxf(mx, __shfl_xor(mx, 16));
      mx = fmaxf(mx, __shfl_xor(mx, 32));
      float m_new = fmaxf(m_i[grp], mx);
      float alpha = __expf(m_i[grp] - m_new);
      float psum = 0.0f;
#pragma unroll
      for (int i = 0; i < 16; i++) {
        float p = __expf(scv[i] - m_new);
        psum += p;
        pb[grp][i] = f2bf(p);
      }
      psum += __shfl_xor(psum, 16);
      psum += __shfl_xor(psum, 32);
      l_i[grp] = l_i[grp] * alpha + psum;
      m_i[grp] = m_new;

      // rebroadcast alpha from col-space (q=c) to row-space (q=g*4+r) via shfl
      f32x4 a4;
#pragma unroll
      for (int r = 0; r < 4; r++) a4[r] = __shfl(alpha, g * 4 + r);
#pragma unroll
      for (int nt = 0; nt < 8; nt++)
#pragma unroll
        for (int r = 0; r < 4; r++) O[grp][nt][r] *= a4[r];
    }

    // PV per group, single Ps buffer (in-wave DS ordering keeps this safe)
#pragma unroll
    for (int grp = 0; grp < 2; grp++) {
#pragma unroll
      for (int mt = 0; mt < 4; mt++) {
        u16x4 p4 = {pb[grp][mt * 4 + 0], pb[grp][mt * 4 + 1],
                    pb[grp][mt * 4 + 2], pb[grp][mt * 4 + 3]};
        *(u16x4*)&Ps[w][c][mt * 16 + g * 4] = p4;
      }
#pragma unroll
      for (int ks = 0; ks < 2; ks++) {
        short8 pf = *(const short8*)&Ps[w][c][ks * 32 + g * 8];
#pragma unroll
        for (int nt = 0; nt < 8; nt++) {
          short8 vf = *(const short8*)&Vt[nt * 16 + c][ks * 32 + g * 8];
          O[grp][nt] = __builtin_amdgcn_mfma_f32_16x16x32_bf16(pf, vf, O[grp][nt], 0, 0, 0);
        }
      }
    }
  }

  // epilogue: O /= l (shfl rebroadcast), write bf16 in place (q region)
#pragma unroll
  for (int grp = 0; grp < 2; grp++) {
    f32x4 li;
#pragma unroll
    for (int r = 0; r < 4; r++) li[r] = 1.0f / __shfl(l_i[grp], g * 4 + r);
#pragma unroll
    for (int nt = 0; nt < 8; nt++)
#pragma unroll
      for (int r = 0; r < 4; r++) {
        size_t addr = (size_t)(b * SEQ + q0 + w * 32 + grp * 16 + g * 4 + r) * QKV_O
                      + h * HD + nt * 16 + c;
        qkv[addr] = f2bf(O[grp][nt][r] * li[r]);
      }
  }
}

// ---------------------------------------------------------------------------
extern "C" void kernel_launch(void* const* d_in, const int* in_sizes, int n_in,
                              void* d_out, int out_size, void* d_ws, size_t ws_size,
                              hipStream_t stream) {
  const float* hidden_f = (const float*)d_in[0];
  const int* positions  = (const int*)d_in[1];
  const float* wqkv_f   = (const float*)d_in[2];
  const float* wo_f     = (const float*)d_in[3];
  const float* qn_f     = (const float*)d_in[4];
  const float* kn_f     = (const float*)d_in[5];
  float* out            = (float*)d_out;  // reference output dtype is float32

  char* ws = (char*)d_ws;
  unsigned short* hidden_c = (unsigned short*)ws;                    // 16,777,216
  unsigned short* wqkv_c   = (unsigned short*)(ws + 16777216);       // 20,971,520
  unsigned short* wo_c     = (unsigned short*)(ws + 37748736);       // 16,777,216
  unsigned short* qn_c     = (unsigned short*)(ws + 54525952);       // 256
  unsigned short* kn_c     = (unsigned short*)(ws + 54526208);       // 256
  unsigned short* qkv      = (unsigned short*)(ws + 54526464);       // 41,943,040
  unsigned short* vt_g     = (unsigned short*)(ws + 96469504);       // 4,194,304  (total ~96 MiB)

  convert_to_bf16<<<1024, 256, 0, stream>>>(hidden_f, hidden_c, NTOK * HID / 4);
  convert_to_bf16<<<1024, 256, 0, stream>>>(wqkv_f, wqkv_c, QKV_O * HID / 4);
  convert_to_bf16<<<1024, 256, 0, stream>>>(wo_f, wo_c, HID * NH * HD / 4);
  convert_to_bf16<<<1, 32, 0, stream>>>(qn_f, qn_c, HD / 4);
  convert_to_bf16<<<1, 32, 0, stream>>>(kn_f, kn_c, HD / 4);

  // K1: qkv = hidden @ w_qkv^T   (4096 x 5120 x 2048), bf16 out
  gemm_bt_bf16<false><<<dim3(QKV_O / 128, NTOK / 128), 256, 0, stream>>>(
      hidden_c, wqkv_c, qkv, HID, HID, QKV_O, HID);
  // K2: rmsnorm + rope, in place on q & k head slots
  normrope<<<NTOK, 256, 0, stream>>>(qkv, positions, qn_c, kn_c);
  // K2b: V transpose into vt_g
  transpose_v<<<dim3(SEQ / 64, NKV, BATCH), 256, 0, stream>>>(qkv, vt_g);
  // K3: MFMA causal GQA attention, attn in place into q region of qkv
  flash_mfma<<<dim3(SEQ / 128, NH, BATCH), 256, 0, stream>>>(qkv, vt_g);
  // K4: out = attn @ w_o^T   (4096 x 2048 x 4096), fp32 out
  gemm_bt_bf16<true><<<dim3(HID / 128, NTOK / 128), 256, 0, stream>>>(
      qkv, wo_c, out, QKV_O, NH * HD, HID, NH * HD);
}